// Round 4
// baseline (1078.681 us; speedup 1.0000x reference)
//
#include <hip/hip_runtime.h>
#include <cstdint>

typedef float float2v __attribute__((ext_vector_type(2)));
typedef _Float16 half2v __attribute__((ext_vector_type(2)));

__device__ inline float2v mk2(float a, float b) { float2v r; r[0] = a; r[1] = b; return r; }

__device__ inline half2v pack2h(float a, float b) {
  return __builtin_bit_cast(half2v, __builtin_amdgcn_cvt_pkrtz(a, b));
}

__device__ inline float fast_rcp(float x) {
#if __has_builtin(__builtin_amdgcn_rcpf)
  return __builtin_amdgcn_rcpf(x);
#else
  return 1.0f / x;
#endif
}

__device__ inline float dot2_acc(half2v a, half2v b, float c) {
#if __has_builtin(__builtin_amdgcn_fdot2)
  return __builtin_amdgcn_fdot2(a, b, c, false);
#else
  c = fmaf((float)a[0], (float)b[0], c);
  return fmaf((float)a[1], (float)b[1], c);
#endif
}

__device__ inline half2v h2(int v) { return __builtin_bit_cast(half2v, v); }

// tanh via Pade(7,7); |err| < 2e-4 for |x| <= 4.5, clamped outside (err <= 2.5e-4).
// One v_rcp on the chain instead of exp+rcp.
__device__ inline float tanh_pade(float x) {
  float xc = fmaxf(fminf(x, 4.5f), -4.5f);
  float r = xc * xc;
  float u = 378.0f + r;
  u = fmaf(r, u, 17325.0f);
  u = fmaf(r, u, 135135.0f);
  float nu = xc * u;
  float d = fmaf(r, 28.0f, 3150.0f);
  d = fmaf(r, d, 62370.0f);
  d = fmaf(r, d, 135135.0f);
  return nu * fast_rcp(d);
}

#define BB 256
#define SS 4096
#define II 32
#define HH 64

// ---------------- prep: Wc = W_ih @ W_in  [64][32], bc = W_ih@b_in + bias ----------------
__global__ __launch_bounds__(256) void prep_kernel(
    const float* __restrict__ W_in, const float* __restrict__ b_in,
    const float* __restrict__ W_ih, const float* __restrict__ bias,
    float* __restrict__ Wc, float* __restrict__ bc) {
  int tid = threadIdx.x;
  int j = tid & 63;
  int iq = tid >> 6;
  float acc[8];
#pragma unroll
  for (int i = 0; i < 8; ++i) acc[i] = 0.f;
  const float* wih = W_ih + j * HH;
  for (int h = 0; h < HH; ++h) {
    float w = wih[h];
    const float* wr = W_in + h * II + iq * 8;
#pragma unroll
    for (int i = 0; i < 8; ++i) acc[i] = fmaf(w, wr[i], acc[i]);
  }
#pragma unroll
  for (int i = 0; i < 8; ++i) Wc[j * II + iq * 8 + i] = acc[i];
  if (iq == 0) {
    float s = 0.f;
    for (int h = 0; h < HH; ++h) s = fmaf(wih[h], b_in[h], s);
    bc[j] = s + bias[j];
  }
}

// ---------------- gemm: pre[row][j] = x[row] . Wc[j] + bc[j]  (f16 out) ----------------
__global__ __launch_bounds__(256) void gemm_pre_kernel(
    const float* __restrict__ x, const float* __restrict__ Wc,
    const float* __restrict__ bc, _Float16* __restrict__ pre) {
  __shared__ __align__(16) float xbuf[64 * II];
  int tid = threadIdx.x;
  int lane = tid & 63;
  int wave = tid >> 6;
  long rowbase = (long)blockIdx.x * 64;
  const float4* xg = (const float4*)(x + rowbase * II);
  float4* xb = (float4*)xbuf;
  xb[tid] = xg[tid];
  xb[tid + 256] = xg[tid + 256];
  float2v w2[16];
  {
    const float4* wr = (const float4*)(Wc + lane * II);
#pragma unroll
    for (int i = 0; i < 8; ++i) {
      float4 q = wr[i];
      w2[2 * i] = mk2(q.x, q.y);
      w2[2 * i + 1] = mk2(q.z, q.w);
    }
  }
  float bcv = bc[lane];
  __syncthreads();
  _Float16* pb = pre + (rowbase + wave * 16) * HH + lane;
#pragma unroll 4
  for (int rr = 0; rr < 16; ++rr) {
    const float4* xr = (const float4*)(xbuf + (wave * 16 + rr) * II);
    float2v a0 = mk2(0, 0), a1 = mk2(0, 0), a2 = mk2(0, 0), a3 = mk2(0, 0);
#pragma unroll
    for (int i = 0; i < 8; i += 2) {
      float4 q = xr[i];
      float4 p = xr[i + 1];
      a0 += mk2(q.x, q.y) * w2[2 * i];
      a1 += mk2(q.z, q.w) * w2[2 * i + 1];
      a2 += mk2(p.x, p.y) * w2[2 * i + 2];
      a3 += mk2(p.z, p.w) * w2[2 * i + 3];
    }
    float2v aa = (a0 + a1) + (a2 + a3);
    pb[(long)rr * HH] = (_Float16)(aa[0] + aa[1] + bcv);
  }
}

// ---------------- scan: one wave per batch; f16 LDS broadcast, poly tanh ----------------
__global__ __launch_bounds__(64) void scan_kernel(
    const float* __restrict__ W_hh, const float* __restrict__ tau,
    const float* __restrict__ W_out, const float* __restrict__ b_out,
    const _Float16* __restrict__ pre, float* __restrict__ out) {
  // tanh ring: 64 rows x 72 f16 (144 B rows: 16B-aligned, breaks bank conflicts for
  // the per-lane output-GEMV reads; broadcast reads are same-address, conflict-free)
  __shared__ __align__(16) _Float16 ring[64 * 72];
  __shared__ __align__(16) _Float16 prebuf[2][64 * HH];  // double-buffered pre chunks
  __shared__ __align__(16) _Float16 woph[64];
  int lane = threadIdx.x;
  int b = blockIdx.x;
  // W_hh row j as 32 packed f16 pairs: wph[m] = (W[j][2m], W[j][2m+1])
  half2v wph[32];
  {
    const float4* wr = (const float4*)(W_hh + lane * HH);
#pragma unroll
    for (int i = 0; i < 16; ++i) {
      float4 q = wr[i];
      wph[2 * i] = pack2h(q.x, q.y);
      wph[2 * i + 1] = pack2h(q.z, q.w);
    }
  }
  float cinv = 1.0f / tau[lane];  // dt = 1.0
  float aco = 1.0f - cinv;
  woph[lane] = (_Float16)W_out[lane];
  float bout = b_out[0];
  ring[63 * 72 + lane] = (_Float16)0.f;  // tanh(h_{-1}) = 0
  const _Float16* preb = pre + (size_t)b * (SS * HH);
  float* outb = out + (size_t)b * SS;
  // prologue: chunk 0 -> LDS (8 KB)
  {
    const float4* src = (const float4*)preb;
    float4* dst = (float4*)prebuf[0];
#pragma unroll
    for (int k = 0; k < 8; ++k) dst[k * 64 + lane] = src[k * 64 + lane];
  }
  float h = 0.0f;
  int cur = 0;
  float pvc = (float)prebuf[0][lane];  // pre for step 0
  for (int c = 0; c < 64; ++c) {
    // register-prefetch next chunk (overlaps the 64 compute steps)
    float4 nxt[8];
    if (c < 63) {
      const float4* src = (const float4*)(preb + (size_t)(c + 1) * (64 * HH));
#pragma unroll
      for (int k = 0; k < 8; ++k) nxt[k] = src[k * 64 + lane];
    }
    const _Float16* ph = prebuf[cur];
#pragma unroll 8
    for (int r = 0; r < 64; ++r) {
      // broadcast-read tanh(h_{t-1}) row: 8 x ds_read_b128, all lanes same address
      const int4* tr = (const int4*)(ring + ((r + 63) & 63) * 72);
      float accs[8];
#pragma unroll
      for (int k = 0; k < 8; ++k) {
        int4 q = tr[k];
        float t0 = dot2_acc(wph[4 * k + 0], h2(q.x), 0.0f);
        t0 = dot2_acc(wph[4 * k + 1], h2(q.y), t0);
        t0 = dot2_acc(wph[4 * k + 2], h2(q.z), t0);
        accs[k] = dot2_acc(wph[4 * k + 3], h2(q.w), t0);
      }
      float dot = ((accs[0] + accs[1]) + (accs[2] + accs[3])) +
                  ((accs[4] + accs[5]) + (accs[6] + accs[7]));
      // h update (tau=1 in practice => contraction; generic code)
      h = fmaf(aco, h, cinv * (dot + pvc));
      // prefetch next step's pre (feeds only the NEXT h update)
      if (r < 63) pvc = (float)ph[(r + 1) * HH + lane];
      float tv = tanh_pade(h);
      ring[r * 72 + lane] = (_Float16)tv;
    }
    // fused output GEMV for this chunk: lane = step index within chunk
    {
      const int4* tr2 = (const int4*)(ring + lane * 72);
      const int4* wv = (const int4*)woph;
      float s0 = 0.f, s1 = 0.f, s2 = 0.f, s3 = 0.f;
#pragma unroll
      for (int k = 0; k < 8; ++k) {
        int4 q = tr2[k];
        int4 w = wv[k];
        s0 = dot2_acc(h2(w.x), h2(q.x), s0);
        s1 = dot2_acc(h2(w.y), h2(q.y), s1);
        s2 = dot2_acc(h2(w.z), h2(q.z), s2);
        s3 = dot2_acc(h2(w.w), h2(q.w), s3);
      }
      outb[c * 64 + lane] = ((s0 + s1) + (s2 + s3)) + bout;
    }
    // stage prefetched chunk into the other LDS buffer, then load next pvc
    if (c < 63) {
      float4* dst = (float4*)prebuf[cur ^ 1];
#pragma unroll
      for (int k = 0; k < 8; ++k) dst[k * 64 + lane] = nxt[k];
      cur ^= 1;
      pvc = (float)prebuf[cur][lane];  // step 0 of next chunk
    }
  }
}

extern "C" void kernel_launch(void* const* d_in, const int* in_sizes, int n_in,
                              void* d_out, int out_size, void* d_ws, size_t ws_size,
                              hipStream_t stream) {
  const float* x     = (const float*)d_in[0];
  const float* W_in  = (const float*)d_in[1];
  const float* b_in  = (const float*)d_in[2];
  const float* W_hh  = (const float*)d_in[3];
  const float* W_ih  = (const float*)d_in[4];
  const float* bias  = (const float*)d_in[5];
  const float* tau   = (const float*)d_in[6];
  const float* W_out = (const float*)d_in[7];
  const float* b_out = (const float*)d_in[8];
  float* out = (float*)d_out;
  char* ws = (char*)d_ws;
  float* Wc = (float*)ws;                    // 8 KB
  float* bc = (float*)(ws + 8192);           // 256 B
  _Float16* pre = (_Float16*)(ws + 16384);   // 64 MiB f16 [B*S][64]

  hipLaunchKernelGGL(prep_kernel, dim3(1), dim3(256), 0, stream,
                     W_in, b_in, W_ih, bias, Wc, bc);
  hipLaunchKernelGGL(gemm_pre_kernel, dim3(16384), dim3(256), 0, stream,
                     x, Wc, bc, pre);
  hipLaunchKernelGGL(scan_kernel, dim3(BB), dim3(64), 0, stream,
                     W_hh, tau, W_out, b_out, pre, out);
}

// Round 5
// 1016.930 us; speedup vs baseline: 1.0607x; 1.0607x over previous
//
#include <hip/hip_runtime.h>
#include <cstdint>

typedef float float2v __attribute__((ext_vector_type(2)));
typedef _Float16 half2v __attribute__((ext_vector_type(2)));

__device__ inline float2v mk2(float a, float b) { float2v r; r[0] = a; r[1] = b; return r; }

__device__ inline half2v pack2h(float a, float b) {
  return __builtin_bit_cast(half2v, __builtin_amdgcn_cvt_pkrtz(a, b));
}

__device__ inline float fast_exp2(float x) {
#if __has_builtin(__builtin_amdgcn_exp2f)
  return __builtin_amdgcn_exp2f(x);
#else
  return exp2f(x);
#endif
}
__device__ inline float fast_rcp(float x) {
#if __has_builtin(__builtin_amdgcn_rcpf)
  return __builtin_amdgcn_rcpf(x);
#else
  return 1.0f / x;
#endif
}

// lane j gets lane (j^1)'s value, VALU-only (DPP quad_perm [1,0,3,2] = 0xB1)
__device__ inline float dpp_xor1(float v) {
#if __has_builtin(__builtin_amdgcn_update_dpp)
  int r = __builtin_amdgcn_update_dpp(0, __builtin_bit_cast(int, v), 0xB1, 0xF, 0xF, true);
  return __builtin_bit_cast(float, r);
#elif __has_builtin(__builtin_amdgcn_mov_dpp)
  int r = __builtin_amdgcn_mov_dpp(__builtin_bit_cast(int, v), 0xB1, 0xF, 0xF, true);
  return __builtin_bit_cast(float, r);
#else
  return __shfl_xor(v, 1, 64);
#endif
}

__device__ inline float dot2_acc(half2v a, half2v b, float c) {
#if __has_builtin(__builtin_amdgcn_fdot2)
  return __builtin_amdgcn_fdot2(a, b, c, false);
#else
  c = fmaf((float)a[0], (float)b[0], c);
  return fmaf((float)a[1], (float)b[1], c);
#endif
}

__device__ inline half2v h2(int v) { return __builtin_bit_cast(half2v, v); }

#define BB 256
#define SS 4096
#define II 32
#define HH 64

// ---------------- prep: Wc = W_ih @ W_in  [64][32], bc = W_ih@b_in + bias ----------------
__global__ __launch_bounds__(256) void prep_kernel(
    const float* __restrict__ W_in, const float* __restrict__ b_in,
    const float* __restrict__ W_ih, const float* __restrict__ bias,
    float* __restrict__ Wc, float* __restrict__ bc) {
  int tid = threadIdx.x;
  int j = tid & 63;
  int iq = tid >> 6;
  float acc[8];
#pragma unroll
  for (int i = 0; i < 8; ++i) acc[i] = 0.f;
  const float* wih = W_ih + j * HH;
  for (int h = 0; h < HH; ++h) {
    float w = wih[h];
    const float* wr = W_in + h * II + iq * 8;
#pragma unroll
    for (int i = 0; i < 8; ++i) acc[i] = fmaf(w, wr[i], acc[i]);
  }
#pragma unroll
  for (int i = 0; i < 8; ++i) Wc[j * II + iq * 8 + i] = acc[i];
  if (iq == 0) {
    float s = 0.f;
    for (int h = 0; h < HH; ++h) s = fmaf(wih[h], b_in[h], s);
    bc[j] = s + bias[j];
  }
}

// ---------------- gemm: preT[batch][j][s] = x[batch,s] . Wc[j] + bc[j]  (f16, TRANSPOSED) ----------------
__global__ __launch_bounds__(256) void gemm_pre_kernel(
    const float* __restrict__ x, const float* __restrict__ Wc,
    const float* __restrict__ bc, _Float16* __restrict__ preT) {
  __shared__ __align__(16) float xbuf[64 * II];
  int tid = threadIdx.x;
  int lane = tid & 63;   // j
  int wave = tid >> 6;   // s sub-block
  long rowbase = (long)blockIdx.x * 64;  // 64 consecutive (batch,s) rows; one batch (4096%64==0)
  const float4* xg = (const float4*)(x + rowbase * II);
  float4* xb = (float4*)xbuf;
  xb[tid] = xg[tid];
  xb[tid + 256] = xg[tid + 256];
  float2v w2[16];
  {
    const float4* wr = (const float4*)(Wc + lane * II);
#pragma unroll
    for (int i = 0; i < 8; ++i) {
      float4 q = wr[i];
      w2[2 * i] = mk2(q.x, q.y);
      w2[2 * i + 1] = mk2(q.z, q.w);
    }
  }
  float bcv = bc[lane];
  __syncthreads();
  float v[16];
#pragma unroll 4
  for (int rr = 0; rr < 16; ++rr) {
    const float4* xr = (const float4*)(xbuf + (wave * 16 + rr) * II);
    float2v a0 = mk2(0, 0), a1 = mk2(0, 0), a2 = mk2(0, 0), a3 = mk2(0, 0);
#pragma unroll
    for (int i = 0; i < 8; i += 2) {
      float4 q = xr[i];
      float4 p = xr[i + 1];
      a0 += mk2(q.x, q.y) * w2[2 * i];
      a1 += mk2(q.z, q.w) * w2[2 * i + 1];
      a2 += mk2(p.x, p.y) * w2[2 * i + 2];
      a3 += mk2(p.z, p.w) * w2[2 * i + 3];
    }
    float2v aa = (a0 + a1) + (a2 + a3);
    v[rr] = aa[0] + aa[1] + bcv;
  }
  // pack 16 f16 and store transposed: preT[batch*S*H + j*S + s], 32B contiguous per lane
  int p8[8];
#pragma unroll
  for (int i = 0; i < 8; ++i) p8[i] = __builtin_bit_cast(int, pack2h(v[2 * i], v[2 * i + 1]));
  int batch = (int)(rowbase >> 12);
  int sb = (int)(rowbase & 4095) + wave * 16;
  _Float16* dst = preT + (size_t)batch * (SS * HH) + (size_t)lane * SS + sb;
  int4* d4 = (int4*)dst;
  int4 q0; q0.x = p8[0]; q0.y = p8[1]; q0.z = p8[2]; q0.w = p8[3];
  int4 q1; q1.x = p8[4]; q1.y = p8[5]; q1.z = p8[6]; q1.w = p8[7];
  d4[0] = q0;
  d4[1] = q1;
}

// ---------------- scan: one wave per batch; pure-VALU chain (readlane broadcast),
//                  pre prefetched 8 steps at a time from global into registers ----------------
__global__ __launch_bounds__(64) void scan_kernel(
    const float* __restrict__ W_hh, const float* __restrict__ tau,
    const float* __restrict__ W_out, const float* __restrict__ b_out,
    const _Float16* __restrict__ preT, float* __restrict__ out) {
  // tanh ring, f16, row stride 80 (160B: 16B-aligned; 4-way max conflict on the
  // per-chunk output GEMV reads; per-step writes are 2-per-dword => free)
  __shared__ __align__(16) _Float16 ring[64 * 80];
  __shared__ __align__(16) _Float16 woph[64];
  int lane = threadIdx.x;
  int b = blockIdx.x;
  // W_hh row j as 32 packed f16 pairs
  half2v wph[32];
  {
    const float4* wr = (const float4*)(W_hh + lane * HH);
#pragma unroll
    for (int i = 0; i < 16; ++i) {
      float4 q = wr[i];
      wph[2 * i] = pack2h(q.x, q.y);
      wph[2 * i + 1] = pack2h(q.z, q.w);
    }
  }
  float cinv = 1.0f / tau[lane];  // dt = 1.0
  float aco = 1.0f - cinv;
  woph[lane] = (_Float16)W_out[lane];
  float bout = b_out[0];
  const _Float16* preb = preT + (size_t)b * (SS * HH) + (size_t)lane * SS;
  float* outb = out + (size_t)b * SS;
  float h = 0.0f;
  half2v pk;  // (t_j, t_{j^1}); t_{-1} = 0
  pk[0] = (_Float16)0.f; pk[1] = (_Float16)0.f;
  int4 pA = *(const int4*)(preb);  // pre for steps 0..7 (8 f16)
  for (int blk = 0; blk < 512; ++blk) {  // 512 blocks x 8 steps
    int4 pB;
    if (blk < 511) pB = *(const int4*)(preb + (size_t)(blk + 1) * 8);  // prefetch next block
    int pw[4];
    pw[0] = pA.x; pw[1] = pA.y; pw[2] = pA.z; pw[3] = pA.w;
    int rbase = (blk & 7) * 8;  // ring row base within 64-step chunk
#pragma unroll
    for (int i = 0; i < 8; ++i) {
      // --- broadcast via 32 readlanes + 8 independent 4-deep dot2 chains ---
      int pkb = __builtin_bit_cast(int, pk);
      float accs[8];
#pragma unroll
      for (int m = 0; m < 8; ++m) {
        int s0 = __builtin_amdgcn_readlane(pkb, 8 * m);
        int s1 = __builtin_amdgcn_readlane(pkb, 8 * m + 2);
        int s2 = __builtin_amdgcn_readlane(pkb, 8 * m + 4);
        int s3 = __builtin_amdgcn_readlane(pkb, 8 * m + 6);
        float t0 = dot2_acc(wph[4 * m], h2(s0), 0.0f);
        t0 = dot2_acc(wph[4 * m + 1], h2(s1), t0);
        t0 = dot2_acc(wph[4 * m + 2], h2(s2), t0);
        accs[m] = dot2_acc(wph[4 * m + 3], h2(s3), t0);
      }
      float dot = ((accs[0] + accs[1]) + (accs[2] + accs[3])) +
                  ((accs[4] + accs[5]) + (accs[6] + accs[7]));
      // --- pre value from register (no memory op on chain) ---
      half2v ph2 = h2(pw[i >> 1]);
      float pv = (float)ph2[i & 1];
      // --- h update ---
      h = fmaf(aco, h, cinv * (dot + pv));
      // --- tanh(h) = 1 - 2/(exp2(2*log2e*h)+1) ---
      float e = fast_exp2(h * 2.885390081777927f);
      float tv = 1.0f - 2.0f * fast_rcp(e + 1.0f);
      // fire-and-forget ring write (only read once per 64 steps)
      ring[(rbase + i) * 80 + lane] = (_Float16)tv;
      // pack (t_j, t_{j^1}) for next step's broadcast
      float to = dpp_xor1(tv);
      pk = pack2h(tv, to);
    }
    pA = pB;
    if ((blk & 7) == 7) {
      // output GEMV for chunk c: lane = step index within chunk
      int c = blk >> 3;
      const int4* tr2 = (const int4*)(ring + lane * 80);
      const int4* wv = (const int4*)woph;
      float s0 = 0.f, s1 = 0.f, s2 = 0.f, s3 = 0.f;
#pragma unroll
      for (int k = 0; k < 8; k += 4) {
        int4 q0 = tr2[k], q1 = tr2[k + 1], q2 = tr2[k + 2], q3 = tr2[k + 3];
        int4 w0 = wv[k], w1 = wv[k + 1], w2_ = wv[k + 2], w3 = wv[k + 3];
        s0 = dot2_acc(h2(w0.x), h2(q0.x), s0); s1 = dot2_acc(h2(w0.y), h2(q0.y), s1);
        s2 = dot2_acc(h2(w0.z), h2(q0.z), s2); s3 = dot2_acc(h2(w0.w), h2(q0.w), s3);
        s0 = dot2_acc(h2(w1.x), h2(q1.x), s0); s1 = dot2_acc(h2(w1.y), h2(q1.y), s1);
        s2 = dot2_acc(h2(w1.z), h2(q1.z), s2); s3 = dot2_acc(h2(w1.w), h2(q1.w), s3);
        s0 = dot2_acc(h2(w2_.x), h2(q2.x), s0); s1 = dot2_acc(h2(w2_.y), h2(q2.y), s1);
        s2 = dot2_acc(h2(w2_.z), h2(q2.z), s2); s3 = dot2_acc(h2(w2_.w), h2(q2.w), s3);
        s0 = dot2_acc(h2(w3.x), h2(q3.x), s0); s1 = dot2_acc(h2(w3.y), h2(q3.y), s1);
        s2 = dot2_acc(h2(w3.z), h2(q3.z), s2); s3 = dot2_acc(h2(w3.w), h2(q3.w), s3);
      }
      outb[c * 64 + lane] = ((s0 + s1) + (s2 + s3)) + bout;
    }
  }
}

extern "C" void kernel_launch(void* const* d_in, const int* in_sizes, int n_in,
                              void* d_out, int out_size, void* d_ws, size_t ws_size,
                              hipStream_t stream) {
  const float* x     = (const float*)d_in[0];
  const float* W_in  = (const float*)d_in[1];
  const float* b_in  = (const float*)d_in[2];
  const float* W_hh  = (const float*)d_in[3];
  const float* W_ih  = (const float*)d_in[4];
  const float* bias  = (const float*)d_in[5];
  const float* tau   = (const float*)d_in[6];
  const float* W_out = (const float*)d_in[7];
  const float* b_out = (const float*)d_in[8];
  float* out = (float*)d_out;
  char* ws = (char*)d_ws;
  float* Wc = (float*)ws;                    // 8 KB
  float* bc = (float*)(ws + 8192);           // 256 B
  _Float16* preT = (_Float16*)(ws + 16384);  // 64 MiB f16, [B][H][S] transposed

  hipLaunchKernelGGL(prep_kernel, dim3(1), dim3(256), 0, stream,
                     W_in, b_in, W_ih, bias, Wc, bc);
  hipLaunchKernelGGL(gemm_pre_kernel, dim3(16384), dim3(256), 0, stream,
                     x, Wc, bc, preT);
  hipLaunchKernelGGL(scan_kernel, dim3(BB), dim3(64), 0, stream,
                     W_hh, tau, W_out, b_out, preT, out);
}